// Round 1
// baseline (3710.021 us; speedup 1.0000x reference)
//
#include <hip/hip_runtime.h>

#define NWG 64

typedef __bf16 bf16x8 __attribute__((ext_vector_type(8)));
typedef float f32x4 __attribute__((ext_vector_type(4)));

__device__ __forceinline__ unsigned short f2bf(float f) {
    union { float f; unsigned u; } v; v.f = f;
    unsigned u = v.u;
    return (unsigned short)((u + 0x7FFFu + ((u >> 16) & 1u)) >> 16);
}
__device__ __forceinline__ float bf2f(unsigned short h) {
    union { unsigned u; float f; } v; v.u = ((unsigned)h) << 16;
    return v.f;
}
__device__ __forceinline__ bf16x8 ld8(const unsigned short* p) {
    union { uint4 u; bf16x8 b; } cv;
    cv.u = *(const uint4*)p;
    return cv.b;
}
__device__ __forceinline__ float sigmoidf_(float x) {
    return 1.0f / (1.0f + __expf(-x));
}

// ---------------- prep: transpose cemb_W, bias sum, zero h state + counter ----
__global__ void k_prep(const float* __restrict__ cemb_W,
                       const float* __restrict__ b_ih, const float* __restrict__ b_hh,
                       float* __restrict__ cWT, float* __restrict__ bsum,
                       unsigned short* __restrict__ hbuf, unsigned* __restrict__ cnt) {
    int i = blockIdx.x * blockDim.x + threadIdx.x;
    int stride = gridDim.x * blockDim.x;
    const int TOT = 32768 + 1024 + 65536 + 1;
    for (; i < TOT; i += stride) {
        if (i < 32768) {
            int idx = i >> 8, e = i & 255;
            cWT[idx * 256 + e] = cemb_W[e * 128 + idx];   // cWT[i][e] = cemb_W[e][i]
        } else if (i < 33792) {
            int g = i - 32768;
            bsum[g] = b_ih[g] + b_hh[g];
        } else if (i < 99328) {
            hbuf[i - 33792] = 0;
        } else {
            cnt[0] = 0;
        }
    }
}

// ---------------- build A_in = [xemb * Cct, onehots] (bf16, rows m = t*128+b) --
__global__ __launch_bounds__(128) void k_build_in(
    const int* __restrict__ c, const int* __restrict__ r,
    const int* __restrict__ rgap, const int* __restrict__ sgap, const int* __restrict__ pcount,
    const float* __restrict__ E, const float* __restrict__ cWT,
    unsigned short* __restrict__ A) {
    int m = blockIdx.x;
    int b = m & 127, t = m >> 7;
    int src = b * 200 + t;
    int x = c[src] + 1024 * r[src];
    int ra = rgap[src], sa = 32 + sgap[src], pa = 64 + pcount[src];
    int e = threadIdx.x;
#pragma unroll
    for (int j = 0; j < 2; ++j) {
        int ee = e + j * 128;
        float cc = cWT[ra * 256 + ee] + cWT[sa * 256 + ee] + cWT[pa * 256 + ee];
        A[(long)m * 384 + ee] = f2bf(E[(long)x * 256 + ee] * cc);
    }
    A[(long)m * 384 + 256 + e] =
        (e == ra || e == sa || e == pa) ? (unsigned short)0x3F80 : (unsigned short)0;
}

// ---------------- build A_out = [h * Cct_shft, onehots] ----------------------
__global__ __launch_bounds__(128) void k_build_out(
    const int* __restrict__ rgap, const int* __restrict__ sgap, const int* __restrict__ pcount,
    const unsigned short* __restrict__ h_all, const float* __restrict__ cWT,
    unsigned short* __restrict__ A) {
    int m = blockIdx.x;
    int b = m & 127, t = m >> 7;
    int src = b * 200 + t;
    int ra = rgap[src], sa = 32 + sgap[src], pa = 64 + pcount[src];
    int e = threadIdx.x;
#pragma unroll
    for (int j = 0; j < 2; ++j) {
        int ee = e + j * 128;
        float cc = cWT[ra * 256 + ee] + cWT[sa * 256 + ee] + cWT[pa * 256 + ee];
        float v = bf2f(h_all[(long)m * 256 + ee]);
        A[(long)m * 384 + ee] = f2bf(v * cc);
    }
    A[(long)m * 384 + 256 + e] =
        (e == ra || e == sa || e == pa) ? (unsigned short)0x3F80 : (unsigned short)0;
}

// ---------------- GEMM: C[M,1024] = A[M,384](bf16) @ Bw[1024,384]^T + bias ----
// EPI==0: store bf16 (xg). EPI==1: sigmoid, store f32 remapped to [B,T,V].
template<int EPI>
__global__ __launch_bounds__(256) void k_gemm(
    const unsigned short* __restrict__ A,
    const float* __restrict__ Bw,
    const float* __restrict__ bias,
    unsigned short* __restrict__ obf,
    float* __restrict__ of) {
    __shared__ unsigned short As[128 * 32];
    __shared__ unsigned short Bs[128 * 32];
    const int m0 = blockIdx.x * 128, n0 = blockIdx.y * 128;
    const int tid = threadIdx.x;
    const int wave = tid >> 6, lane = tid & 63;
    const int wm = wave >> 1, wn = wave & 1;
    const int n = lane & 15, q = lane >> 4;
    f32x4 acc[4][4] = {};
    for (int ks = 0; ks < 12; ++ks) {
        __syncthreads();
        {   // stage A tile 128x32 bf16 (2 x 16B per thread)
            int rr = tid >> 2, cc = (tid & 3) * 8;
            const unsigned short* g = A + (long)(m0 + rr) * 384 + ks * 32 + cc;
            uint4 v0 = *(const uint4*)g;
            uint4 v1 = *(const uint4*)(g + 64 * 384);
            *(uint4*)(&As[rr * 32 + cc]) = v0;
            *(uint4*)(&As[(rr + 64) * 32 + cc]) = v1;
        }
        {   // stage B tile 128x32: f32 -> bf16
            int rr = tid >> 3, cc = (tid & 7) * 4;
#pragma unroll
            for (int j = 0; j < 4; ++j) {
                int row = j * 32 + rr;
                float4 f = *(const float4*)(Bw + (long)(n0 + row) * 384 + ks * 32 + cc);
                ushort4 h;
                h.x = f2bf(f.x); h.y = f2bf(f.y); h.z = f2bf(f.z); h.w = f2bf(f.w);
                *(ushort4*)(&Bs[row * 32 + cc]) = h;
            }
        }
        __syncthreads();
        bf16x8 af[4], bfr[4];
#pragma unroll
        for (int mt = 0; mt < 4; ++mt)
            af[mt] = ld8(&As[(wm * 64 + mt * 16 + n) * 32 + q * 8]);
#pragma unroll
        for (int nt = 0; nt < 4; ++nt)
            bfr[nt] = ld8(&Bs[(wn * 64 + nt * 16 + n) * 32 + q * 8]);
#pragma unroll
        for (int mt = 0; mt < 4; ++mt)
#pragma unroll
            for (int nt = 0; nt < 4; ++nt)
                acc[mt][nt] = __builtin_amdgcn_mfma_f32_16x16x32_bf16(
                    af[mt], bfr[nt], acc[mt][nt], 0, 0, 0);
    }
#pragma unroll
    for (int mt = 0; mt < 4; ++mt) {
#pragma unroll
        for (int nt = 0; nt < 4; ++nt) {
            int col = n0 + wn * 64 + nt * 16 + n;
            float bv = bias[col];
#pragma unroll
            for (int rg = 0; rg < 4; ++rg) {
                int row = m0 + wm * 64 + mt * 16 + q * 4 + rg;
                float v = acc[mt][nt][rg] + bv;
                if (EPI == 0) {
                    obf[(long)row * 1024 + col] = f2bf(v);
                } else {
                    int bb = row & 127, tt = row >> 7;
                    of[((long)bb * 200 + tt) * 1024 + col] = sigmoidf_(v);
                }
            }
        }
    }
}

// ---------------- persistent LSTM: 64 WGs, WG w owns h-cols [4w,4w+4) ---------
__global__ __launch_bounds__(256, 1) void k_lstm(
    const unsigned short* __restrict__ xg,   // [25600][1024] bf16, m = t*128+b
    const float* __restrict__ W_hh,          // [1024][256] f32
    unsigned short* __restrict__ hbuf,       // [2][128][256] bf16
    unsigned short* __restrict__ h_all,      // [25600][256] bf16
    unsigned* __restrict__ cnt) {
    const int w = blockIdx.x;
    const int tid = threadIdx.x;
    const int wave = tid >> 6, lane = tid & 63;
    const int n = lane & 15, q = lane >> 4;
    // frag col n -> gate type n>>2 (i,f,g,o), local hcol n&3
    const int grow = (n >> 2) * 256 + 4 * w + (n & 3);

    __shared__ unsigned short Wl[16 * 256];  // W_hh slice bf16 [frag-col][k]
    __shared__ float cst[128 * 4];           // c state [batch][local hcol]

    for (int i = tid; i < 16 * 256; i += 256) {
        int rn = i >> 8, k = i & 255;
        int g = (rn >> 2) * 256 + 4 * w + (rn & 3);
        Wl[i] = f2bf(W_hh[(long)g * 256 + k]);
    }
    for (int i = tid; i < 512; i += 256) cst[i] = 0.f;
    __syncthreads();

    bf16x8 Bf[8];
#pragma unroll
    for (int ks = 0; ks < 8; ++ks)
        Bf[ks] = ld8(&Wl[n * 256 + ks * 32 + q * 8]);

    const int rowbase = wave * 32;

    for (int t = 0; t < 200; ++t) {
        const unsigned short* hp = hbuf + (t & 1) * (128 * 256);
        unsigned short* hn = hbuf + ((t + 1) & 1) * (128 * 256);

        // prefetch this lane's xg values (gates precomputed incl. bias)
        float xv[2][4];
#pragma unroll
        for (int mt = 0; mt < 2; ++mt)
#pragma unroll
            for (int rg = 0; rg < 4; ++rg) {
                int row = rowbase + mt * 16 + q * 4 + rg;
                xv[mt][rg] = bf2f(xg[(long)(t * 128 + row) * 1024 + grow]);
            }

        f32x4 acc[2] = {};
#pragma unroll
        for (int mt = 0; mt < 2; ++mt) {
#pragma unroll
            for (int ks = 0; ks < 8; ++ks) {
                bf16x8 af = ld8(&hp[(rowbase + mt * 16 + n) * 256 + ks * 32 + q * 8]);
                acc[mt] = __builtin_amdgcn_mfma_f32_16x16x32_bf16(af, Bf[ks], acc[mt], 0, 0, 0);
            }
        }

#pragma unroll
        for (int mt = 0; mt < 2; ++mt) {
#pragma unroll
            for (int rg = 0; rg < 4; ++rg) {
                float gv = acc[mt][rg] + xv[mt][rg];
                int base = lane & 48;
                int j = n & 3;
                float iv = __shfl(gv, base + j, 64);
                float fv = __shfl(gv, base + 4 + j, 64);
                float gg = __shfl(gv, base + 8 + j, 64);
                float ov = __shfl(gv, base + 12 + j, 64);
                int row = rowbase + mt * 16 + q * 4 + rg;
                float co = cst[row * 4 + j];
                float cn = sigmoidf_(fv) * co + sigmoidf_(iv) * tanhf(gg);
                float hv = sigmoidf_(ov) * tanhf(cn);
                if (n < 4) {
                    cst[row * 4 + j] = cn;
                    unsigned short hb = f2bf(hv);
                    hn[row * 256 + 4 * w + n] = hb;
                    h_all[(long)(t * 128 + row) * 256 + 4 * w + n] = hb;
                }
            }
        }

        // device-scope barrier across the 64 persistent WGs
        __threadfence();
        __syncthreads();
        if (tid == 0) {
            __hip_atomic_fetch_add(cnt, 1u, __ATOMIC_ACQ_REL, __HIP_MEMORY_SCOPE_AGENT);
            unsigned target = (unsigned)(NWG * (t + 1));
            while (__hip_atomic_load(cnt, __ATOMIC_ACQUIRE, __HIP_MEMORY_SCOPE_AGENT) < target)
                __builtin_amdgcn_s_sleep(2);
        }
        __syncthreads();
        __threadfence();
    }
}

extern "C" void kernel_launch(void* const* d_in, const int* in_sizes, int n_in,
                              void* d_out, int out_size, void* d_ws, size_t ws_size,
                              hipStream_t stream) {
    const int* c        = (const int*)d_in[0];
    const int* r        = (const int*)d_in[1];
    const int* rgap     = (const int*)d_in[2];
    const int* sgap     = (const int*)d_in[3];
    const int* pcount   = (const int*)d_in[4];
    const int* s_rgap   = (const int*)d_in[5];
    const int* s_sgap   = (const int*)d_in[6];
    const int* s_pcount = (const int*)d_in[7];
    const float* E      = (const float*)d_in[8];
    const float* cemb_W = (const float*)d_in[9];
    const float* W_ih   = (const float*)d_in[10];
    const float* W_hh   = (const float*)d_in[11];
    const float* b_ih   = (const float*)d_in[12];
    const float* b_hh   = (const float*)d_in[13];
    const float* out_W  = (const float*)d_in[14];
    const float* out_b  = (const float*)d_in[15];

    char* ws = (char*)d_ws;
    float* cWT            = (float*)(ws);                       // 131072 B
    float* bsum           = (float*)(ws + 131072);              // 4096 B
    unsigned* cnt         = (unsigned*)(ws + 135168);           // 4096 B
    unsigned short* hbuf  = (unsigned short*)(ws + 139264);     // 131072 B
    unsigned short* h_all = (unsigned short*)(ws + 270336);     // 13107200 B
    unsigned short* Abuf  = (unsigned short*)(ws + 13377536);   // 19660800 B (A_in, reused as A_out)
    unsigned short* xg    = (unsigned short*)(ws + 33038336);   // 52428800 B

    k_prep<<<256, 256, 0, stream>>>(cemb_W, b_ih, b_hh, cWT, bsum, hbuf, cnt);
    k_build_in<<<25600, 128, 0, stream>>>(c, r, rgap, sgap, pcount, E, cWT, Abuf);
    k_gemm<0><<<dim3(200, 8), 256, 0, stream>>>(Abuf, W_ih, bsum, xg, nullptr);
    k_lstm<<<NWG, 256, 0, stream>>>(xg, W_hh, hbuf, h_all, cnt);
    k_build_out<<<25600, 128, 0, stream>>>(s_rgap, s_sgap, s_pcount, h_all, cWT, Abuf);
    k_gemm<1><<<dim3(200, 8), 256, 0, stream>>>(Abuf, out_W, out_b, nullptr, (float*)d_out);
}

// Round 2
// 1126.130 us; speedup vs baseline: 3.2945x; 3.2945x over previous
//
#include <hip/hip_runtime.h>

typedef __bf16 bf16x8 __attribute__((ext_vector_type(8)));
typedef float f32x4 __attribute__((ext_vector_type(4)));

__device__ __forceinline__ unsigned short f2bf(float f) {
    union { float f; unsigned u; } v; v.f = f;
    unsigned u = v.u;
    return (unsigned short)((u + 0x7FFFu + ((u >> 16) & 1u)) >> 16);
}
__device__ __forceinline__ float bf2f(unsigned short h) {
    union { unsigned u; float f; } v; v.u = ((unsigned)h) << 16;
    return v.f;
}
__device__ __forceinline__ bf16x8 ld8(const unsigned short* p) {
    union { uint4 u; bf16x8 b; } cv;
    cv.u = *(const uint4*)p;
    return cv.b;
}
__device__ __forceinline__ float sigmoidf_(float x) {
    return __builtin_amdgcn_rcpf(1.0f + __expf(-x));
}
__device__ __forceinline__ float tanhf_(float x) {
    float xc = fminf(fmaxf(x, -15.0f), 15.0f);
    float e = __expf(-2.0f * xc);
    return (1.0f - e) * __builtin_amdgcn_rcpf(1.0f + e);
}

// ---------------- prep: transpose cemb_W, bias sum, W_hh -> bf16 --------------
__global__ void k_prep(const float* __restrict__ cemb_W,
                       const float* __restrict__ b_ih, const float* __restrict__ b_hh,
                       const float* __restrict__ W_hh,
                       float* __restrict__ cWT, float* __restrict__ bsum,
                       unsigned short* __restrict__ Wbf) {
    int i = blockIdx.x * blockDim.x + threadIdx.x;
    int stride = gridDim.x * blockDim.x;
    const int TOT = 32768 + 1024 + 262144;
    for (; i < TOT; i += stride) {
        if (i < 32768) {
            int idx = i >> 8, e = i & 255;
            cWT[idx * 256 + e] = cemb_W[e * 128 + idx];   // cWT[i][e] = cemb_W[e][i]
        } else if (i < 33792) {
            int g = i - 32768;
            bsum[g] = b_ih[g] + b_hh[g];
        } else {
            int j = i - 33792;
            Wbf[j] = f2bf(W_hh[j]);
        }
    }
}

// ---------------- build A_in = [xemb * Cct, onehots] (bf16, rows m = t*128+b) --
__global__ __launch_bounds__(128) void k_build_in(
    const int* __restrict__ c, const int* __restrict__ r,
    const int* __restrict__ rgap, const int* __restrict__ sgap, const int* __restrict__ pcount,
    const float* __restrict__ E, const float* __restrict__ cWT,
    unsigned short* __restrict__ A) {
    int m = blockIdx.x;
    int b = m & 127, t = m >> 7;
    int src = b * 200 + t;
    int x = c[src] + 1024 * r[src];
    int ra = rgap[src], sa = 32 + sgap[src], pa = 64 + pcount[src];
    int e = threadIdx.x;
#pragma unroll
    for (int j = 0; j < 2; ++j) {
        int ee = e + j * 128;
        float cc = cWT[ra * 256 + ee] + cWT[sa * 256 + ee] + cWT[pa * 256 + ee];
        A[(long)m * 384 + ee] = f2bf(E[(long)x * 256 + ee] * cc);
    }
    A[(long)m * 384 + 256 + e] =
        (e == ra || e == sa || e == pa) ? (unsigned short)0x3F80 : (unsigned short)0;
}

// ---------------- build A_out = [h * Cct_shft, onehots] ----------------------
__global__ __launch_bounds__(128) void k_build_out(
    const int* __restrict__ rgap, const int* __restrict__ sgap, const int* __restrict__ pcount,
    const unsigned short* __restrict__ h_all, const float* __restrict__ cWT,
    unsigned short* __restrict__ A) {
    int m = blockIdx.x;
    int b = m & 127, t = m >> 7;
    int src = b * 200 + t;
    int ra = rgap[src], sa = 32 + sgap[src], pa = 64 + pcount[src];
    int e = threadIdx.x;
#pragma unroll
    for (int j = 0; j < 2; ++j) {
        int ee = e + j * 128;
        float cc = cWT[ra * 256 + ee] + cWT[sa * 256 + ee] + cWT[pa * 256 + ee];
        float v = bf2f(h_all[(long)m * 256 + ee]);
        A[(long)m * 384 + ee] = f2bf(v * cc);
    }
    A[(long)m * 384 + 256 + e] =
        (e == ra || e == sa || e == pa) ? (unsigned short)0x3F80 : (unsigned short)0;
}

// ---------------- GEMM: C[M,1024] = A[M,384](bf16) @ Bw[1024,384]^T + bias ----
template<int EPI>
__global__ __launch_bounds__(256) void k_gemm(
    const unsigned short* __restrict__ A,
    const float* __restrict__ Bw,
    const float* __restrict__ bias,
    unsigned short* __restrict__ obf,
    float* __restrict__ of) {
    __shared__ unsigned short As[128 * 32];
    __shared__ unsigned short Bs[128 * 32];
    const int m0 = blockIdx.x * 128, n0 = blockIdx.y * 128;
    const int tid = threadIdx.x;
    const int wave = tid >> 6, lane = tid & 63;
    const int wm = wave >> 1, wn = wave & 1;
    const int n = lane & 15, q = lane >> 4;
    f32x4 acc[4][4] = {};
    for (int ks = 0; ks < 12; ++ks) {
        __syncthreads();
        {
            int rr = tid >> 2, cc = (tid & 3) * 8;
            const unsigned short* g = A + (long)(m0 + rr) * 384 + ks * 32 + cc;
            uint4 v0 = *(const uint4*)g;
            uint4 v1 = *(const uint4*)(g + 64 * 384);
            *(uint4*)(&As[rr * 32 + cc]) = v0;
            *(uint4*)(&As[(rr + 64) * 32 + cc]) = v1;
        }
        {
            int rr = tid >> 3, cc = (tid & 7) * 4;
#pragma unroll
            for (int j = 0; j < 4; ++j) {
                int row = j * 32 + rr;
                float4 f = *(const float4*)(Bw + (long)(n0 + row) * 384 + ks * 32 + cc);
                ushort4 h;
                h.x = f2bf(f.x); h.y = f2bf(f.y); h.z = f2bf(f.z); h.w = f2bf(f.w);
                *(ushort4*)(&Bs[row * 32 + cc]) = h;
            }
        }
        __syncthreads();
        bf16x8 af[4], bfr[4];
#pragma unroll
        for (int mt = 0; mt < 4; ++mt)
            af[mt] = ld8(&As[(wm * 64 + mt * 16 + n) * 32 + q * 8]);
#pragma unroll
        for (int nt = 0; nt < 4; ++nt)
            bfr[nt] = ld8(&Bs[(wn * 64 + nt * 16 + n) * 32 + q * 8]);
#pragma unroll
        for (int mt = 0; mt < 4; ++mt)
#pragma unroll
            for (int nt = 0; nt < 4; ++nt)
                acc[mt][nt] = __builtin_amdgcn_mfma_f32_16x16x32_bf16(
                    af[mt], bfr[nt], acc[mt][nt], 0, 0, 0);
    }
#pragma unroll
    for (int mt = 0; mt < 4; ++mt) {
#pragma unroll
        for (int nt = 0; nt < 4; ++nt) {
            int col = n0 + wn * 64 + nt * 16 + n;
            float bv = bias[col];
#pragma unroll
            for (int rg = 0; rg < 4; ++rg) {
                int row = m0 + wm * 64 + mt * 16 + q * 4 + rg;
                float v = acc[mt][nt][rg] + bv;
                if (EPI == 0) {
                    obf[(long)row * 1024 + col] = f2bf(v);
                } else {
                    int bb = row & 127, tt = row >> 7;
                    of[((long)bb * 200 + tt) * 1024 + col] = sigmoidf_(v);
                }
            }
        }
    }
}

// ---------------- LSTM: batch-split, NO inter-WG sync ------------------------
// 32 WGs x 4 batch rows x 4 waves(512 VGPR). Wave owns 64 hidden units.
// W_hh bf16: 12 col-tiles/wave resident in VGPRs (384), 4 col-tiles in LDS.
// A-frag rows replicated x4 -> every lane holds all 4 rows' gates in-lane.
#define HB_STRIDE 264
__global__ __launch_bounds__(256, 1) void k_lstm(
    const unsigned short* __restrict__ xg,   // [200*128][1024] bf16, m = t*128+b
    const unsigned short* __restrict__ Wbf,  // [1024][256] bf16
    unsigned short* __restrict__ h_all) {    // [200*128][256] bf16
    __shared__ unsigned short wlds[4 * 4 * 8 * 512];  // 128KB frag-linear
    __shared__ unsigned short xbuf[2][4 * 1024];      // 16KB double-buffered xg slab
    __shared__ unsigned short hb[2][4 * HB_STRIDE];   // h state, padded stride

    const int tid = threadIdx.x;
    const int w = tid >> 6, lane = tid & 63;
    const int n = lane & 15, q = lane >> 4;
    const int b0 = blockIdx.x * 4;  // this WG's batch rows [b0, b0+4)

    // ---- resident W fragments: ct = ub*4+g, ub=0..2 (cts 0..11) ----
    bf16x8 wr[12][8];
#pragma unroll
    for (int ct = 0; ct < 12; ++ct) {
        const int ub = ct >> 2, g = ct & 3;
        const int col = g * 256 + w * 64 + ub * 16 + n;
        const unsigned short* src = Wbf + col * 256 + q * 8;
#pragma unroll
        for (int kk = 0; kk < 8; ++kk)
            wr[ct][kk] = ld8(src + kk * 32);
    }
    // ---- streamed W fragments (ub=3) into LDS, frag-linear ----
#pragma unroll
    for (int g2 = 0; g2 < 4; ++g2) {
        const int col = g2 * 256 + w * 64 + 48 + n;
        const unsigned short* src = Wbf + col * 256 + q * 8;
#pragma unroll
        for (int kk = 0; kk < 8; ++kk) {
            uint4 v = *(const uint4*)(src + kk * 32);
            *(uint4*)(&wlds[((w * 4 + g2) * 8 + kk) * 512 + lane * 8]) = v;
        }
    }
    // ---- zero h buffers, stage xg t=0 ----
    for (int i = tid; i < 2 * 4 * HB_STRIDE; i += 256) {
        hb[0][i & (4 * HB_STRIDE - 1) ? 0 : 0] = 0;  // avoid UB on odd size: plain loop below
    }
    for (int i = tid; i < 4 * HB_STRIDE; i += 256) { hb[0][i] = 0; hb[1][i] = 0; }
    {
        const unsigned short* slab = xg + ((long)0 * 128 + b0) * 1024 + w * 1024 + lane * 16;
        uint4 v0 = *(const uint4*)slab;
        uint4 v1 = *(const uint4*)(slab + 8);
        *(uint4*)(&xbuf[0][w * 1024 + lane * 16]) = v0;
        *(uint4*)(&xbuf[0][w * 1024 + lane * 16 + 8]) = v1;
    }
    __syncthreads();

    const int u = w * 64 + q * 16 + n;  // this lane's hidden unit
    float cs[4] = {0.f, 0.f, 0.f, 0.f};

    for (int t = 0; t < 200; ++t) {
        const int cur = t & 1, nxt = cur ^ 1;
        // prefetch next xg slab into regs (clamped at the tail)
        const int t2 = (t + 1 < 200) ? t + 1 : 199;
        const unsigned short* slab = xg + ((long)t2 * 128 + b0) * 1024 + w * 1024 + lane * 16;
        uint4 pv0 = *(const uint4*)slab;
        uint4 pv1 = *(const uint4*)(slab + 8);

        // ---- gates = h @ W^T : 16 col-tiles x 8 k-slices ----
        f32x4 acc[16] = {};
#pragma unroll
        for (int kk = 0; kk < 8; ++kk) {
            bf16x8 a = ld8(&hb[cur][(n & 3) * HB_STRIDE + kk * 32 + q * 8]);
#pragma unroll
            for (int ct = 0; ct < 12; ++ct)
                acc[ct] = __builtin_amdgcn_mfma_f32_16x16x32_bf16(a, wr[ct][kk], acc[ct], 0, 0, 0);
#pragma unroll
            for (int g2 = 0; g2 < 4; ++g2) {
                bf16x8 wf = ld8(&wlds[((w * 4 + g2) * 8 + kk) * 512 + lane * 8]);
                acc[12 + g2] = __builtin_amdgcn_mfma_f32_16x16x32_bf16(a, wf, acc[12 + g2], 0, 0, 0);
            }
        }

        // ---- in-lane gate select: this lane's ub == q (ct = ub*4+g) ----
        f32x4 vg[4];
#pragma unroll
        for (int g2 = 0; g2 < 4; ++g2) {
            f32x4 lo = (q & 1) ? acc[4 + g2] : acc[g2];
            f32x4 hi = (q & 1) ? acc[12 + g2] : acc[8 + g2];
            vg[g2] = (q & 2) ? hi : lo;
        }

        // ---- elementwise LSTM update, 4 rows (replication: acc row rg == batch row rg)
#pragma unroll
        for (int r = 0; r < 4; ++r) {
            float iv = vg[0][r] + bf2f(xbuf[cur][r * 1024 + 0 * 256 + u]);
            float fv = vg[1][r] + bf2f(xbuf[cur][r * 1024 + 1 * 256 + u]);
            float gg = vg[2][r] + bf2f(xbuf[cur][r * 1024 + 2 * 256 + u]);
            float ov = vg[3][r] + bf2f(xbuf[cur][r * 1024 + 3 * 256 + u]);
            float cn = sigmoidf_(fv) * cs[r] + sigmoidf_(iv) * tanhf_(gg);
            float hv = sigmoidf_(ov) * tanhf_(cn);
            cs[r] = cn;
            unsigned short hbv = f2bf(hv);
            hb[nxt][r * HB_STRIDE + u] = hbv;
            h_all[((long)t * 128 + b0 + r) * 256 + u] = hbv;
        }

        // ---- write prefetched xg slab into the other buffer ----
        *(uint4*)(&xbuf[nxt][w * 1024 + lane * 16]) = pv0;
        *(uint4*)(&xbuf[nxt][w * 1024 + lane * 16 + 8]) = pv1;
        __syncthreads();
    }
}

extern "C" void kernel_launch(void* const* d_in, const int* in_sizes, int n_in,
                              void* d_out, int out_size, void* d_ws, size_t ws_size,
                              hipStream_t stream) {
    const int* c        = (const int*)d_in[0];
    const int* r        = (const int*)d_in[1];
    const int* rgap     = (const int*)d_in[2];
    const int* sgap     = (const int*)d_in[3];
    const int* pcount   = (const int*)d_in[4];
    const int* s_rgap   = (const int*)d_in[5];
    const int* s_sgap   = (const int*)d_in[6];
    const int* s_pcount = (const int*)d_in[7];
    const float* E      = (const float*)d_in[8];
    const float* cemb_W = (const float*)d_in[9];
    const float* W_ih   = (const float*)d_in[10];
    const float* W_hh   = (const float*)d_in[11];
    const float* b_ih   = (const float*)d_in[12];
    const float* b_hh   = (const float*)d_in[13];
    const float* out_W  = (const float*)d_in[14];
    const float* out_b  = (const float*)d_in[15];

    char* ws = (char*)d_ws;
    float* cWT            = (float*)(ws);                       // 131072 B
    float* bsum           = (float*)(ws + 131072);              // 4096 B
    unsigned short* Wbf   = (unsigned short*)(ws + 135168);     // 524288 B
    unsigned short* h_all = (unsigned short*)(ws + 659456);     // 13107200 B
    unsigned short* Abuf  = (unsigned short*)(ws + 13766656);   // 19660800 B
    unsigned short* xg    = (unsigned short*)(ws + 33427456);   // 52428800 B

    k_prep<<<256, 256, 0, stream>>>(cemb_W, b_ih, b_hh, W_hh, cWT, bsum, Wbf);
    k_build_in<<<25600, 128, 0, stream>>>(c, r, rgap, sgap, pcount, E, cWT, Abuf);
    k_gemm<0><<<dim3(200, 8), 256, 0, stream>>>(Abuf, W_ih, bsum, xg, nullptr);
    k_lstm<<<32, 256, 0, stream>>>(xg, Wbf, h_all);
    k_build_out<<<25600, 128, 0, stream>>>(s_rgap, s_sgap, s_pcount, h_all, cWT, Abuf);
    k_gemm<1><<<dim3(200, 8), 256, 0, stream>>>(Abuf, out_W, out_b, nullptr, (float*)d_out);
}

// Round 3
// 657.925 us; speedup vs baseline: 5.6390x; 1.7116x over previous
//
#include <hip/hip_runtime.h>

typedef __bf16 bf16x8 __attribute__((ext_vector_type(8)));
typedef float f32x4 __attribute__((ext_vector_type(4)));

__device__ __forceinline__ unsigned short f2bf(float f) {
    union { float f; unsigned u; } v; v.f = f;
    unsigned u = v.u;
    return (unsigned short)((u + 0x7FFFu + ((u >> 16) & 1u)) >> 16);
}
__device__ __forceinline__ float bf2f(unsigned short h) {
    union { unsigned u; float f; } v; v.u = ((unsigned)h) << 16;
    return v.f;
}
__device__ __forceinline__ bf16x8 ld8(const unsigned short* p) {
    union { uint4 u; bf16x8 b; } cv;
    cv.u = *(const uint4*)p;
    return cv.b;
}
__device__ __forceinline__ float sigmoidf_(float x) {
    return __builtin_amdgcn_rcpf(1.0f + __expf(-x));
}
__device__ __forceinline__ float tanhf_(float x) {
    float xc = fminf(fmaxf(x, -15.0f), 15.0f);
    float e = __expf(-2.0f * xc);
    return (1.0f - e) * __builtin_amdgcn_rcpf(1.0f + e);
}

// ---------------- prep: transpose cemb_W, bias sum, W_hh -> bf16 --------------
__global__ void k_prep(const float* __restrict__ cemb_W,
                       const float* __restrict__ b_ih, const float* __restrict__ b_hh,
                       const float* __restrict__ W_hh,
                       float* __restrict__ cWT, float* __restrict__ bsum,
                       unsigned short* __restrict__ Wbf) {
    int i = blockIdx.x * blockDim.x + threadIdx.x;
    int stride = gridDim.x * blockDim.x;
    const int TOT = 32768 + 1024 + 262144;
    for (; i < TOT; i += stride) {
        if (i < 32768) {
            int idx = i >> 8, e = i & 255;
            cWT[idx * 256 + e] = cemb_W[e * 128 + idx];   // cWT[i][e] = cemb_W[e][i]
        } else if (i < 33792) {
            int g = i - 32768;
            bsum[g] = b_ih[g] + b_hh[g];
        } else {
            int j = i - 33792;
            Wbf[j] = f2bf(W_hh[j]);
        }
    }
}

// ---------------- build A_in = [xemb * Cct, onehots] (bf16, rows m = t*128+b) --
__global__ __launch_bounds__(128) void k_build_in(
    const int* __restrict__ c, const int* __restrict__ r,
    const int* __restrict__ rgap, const int* __restrict__ sgap, const int* __restrict__ pcount,
    const float* __restrict__ E, const float* __restrict__ cWT,
    unsigned short* __restrict__ A) {
    int m = blockIdx.x;
    int b = m & 127, t = m >> 7;
    int src = b * 200 + t;
    int x = c[src] + 1024 * r[src];
    int ra = rgap[src], sa = 32 + sgap[src], pa = 64 + pcount[src];
    int e = threadIdx.x;
#pragma unroll
    for (int j = 0; j < 2; ++j) {
        int ee = e + j * 128;
        float cc = cWT[ra * 256 + ee] + cWT[sa * 256 + ee] + cWT[pa * 256 + ee];
        A[(long)m * 384 + ee] = f2bf(E[(long)x * 256 + ee] * cc);
    }
    A[(long)m * 384 + 256 + e] =
        (e == ra || e == sa || e == pa) ? (unsigned short)0x3F80 : (unsigned short)0;
}

// ---------------- build A_out = [h * Cct_shft, onehots] ----------------------
__global__ __launch_bounds__(128) void k_build_out(
    const int* __restrict__ rgap, const int* __restrict__ sgap, const int* __restrict__ pcount,
    const unsigned short* __restrict__ h_all, const float* __restrict__ cWT,
    unsigned short* __restrict__ A) {
    int m = blockIdx.x;
    int b = m & 127, t = m >> 7;
    int src = b * 200 + t;
    int ra = rgap[src], sa = 32 + sgap[src], pa = 64 + pcount[src];
    int e = threadIdx.x;
#pragma unroll
    for (int j = 0; j < 2; ++j) {
        int ee = e + j * 128;
        float cc = cWT[ra * 256 + ee] + cWT[sa * 256 + ee] + cWT[pa * 256 + ee];
        float v = bf2f(h_all[(long)m * 256 + ee]);
        A[(long)m * 384 + ee] = f2bf(v * cc);
    }
    A[(long)m * 384 + 256 + e] =
        (e == ra || e == sa || e == pa) ? (unsigned short)0x3F80 : (unsigned short)0;
}

// ---------------- GEMM: C[M,1024] = A[M,384](bf16) @ Bw[1024,384]^T + bias ----
// EPI==0: store bf16 xg, GATE-INTERLEAVED: xg[row*1024 + (col&255)*4 + (col>>8)]
// EPI==1: sigmoid, store f32 remapped to [B,T,V].
template<int EPI>
__global__ __launch_bounds__(256) void k_gemm(
    const unsigned short* __restrict__ A,
    const float* __restrict__ Bw,
    const float* __restrict__ bias,
    unsigned short* __restrict__ obf,
    float* __restrict__ of) {
    __shared__ unsigned short As[128 * 32];
    __shared__ unsigned short Bs[128 * 32];
    const int m0 = blockIdx.x * 128, n0 = blockIdx.y * 128;
    const int tid = threadIdx.x;
    const int wave = tid >> 6, lane = tid & 63;
    const int wm = wave >> 1, wn = wave & 1;
    const int n = lane & 15, q = lane >> 4;
    f32x4 acc[4][4] = {};
    for (int ks = 0; ks < 12; ++ks) {
        __syncthreads();
        {
            int rr = tid >> 2, cc = (tid & 3) * 8;
            const unsigned short* g = A + (long)(m0 + rr) * 384 + ks * 32 + cc;
            uint4 v0 = *(const uint4*)g;
            uint4 v1 = *(const uint4*)(g + 64 * 384);
            *(uint4*)(&As[rr * 32 + cc]) = v0;
            *(uint4*)(&As[(rr + 64) * 32 + cc]) = v1;
        }
        {
            int rr = tid >> 3, cc = (tid & 7) * 4;
#pragma unroll
            for (int j = 0; j < 4; ++j) {
                int row = j * 32 + rr;
                float4 f = *(const float4*)(Bw + (long)(n0 + row) * 384 + ks * 32 + cc);
                ushort4 h;
                h.x = f2bf(f.x); h.y = f2bf(f.y); h.z = f2bf(f.z); h.w = f2bf(f.w);
                *(ushort4*)(&Bs[row * 32 + cc]) = h;
            }
        }
        __syncthreads();
        bf16x8 af[4], bfr[4];
#pragma unroll
        for (int mt = 0; mt < 4; ++mt)
            af[mt] = ld8(&As[(wm * 64 + mt * 16 + n) * 32 + q * 8]);
#pragma unroll
        for (int nt = 0; nt < 4; ++nt)
            bfr[nt] = ld8(&Bs[(wn * 64 + nt * 16 + n) * 32 + q * 8]);
#pragma unroll
        for (int mt = 0; mt < 4; ++mt)
#pragma unroll
            for (int nt = 0; nt < 4; ++nt)
                acc[mt][nt] = __builtin_amdgcn_mfma_f32_16x16x32_bf16(
                    af[mt], bfr[nt], acc[mt][nt], 0, 0, 0);
    }
#pragma unroll
    for (int mt = 0; mt < 4; ++mt) {
#pragma unroll
        for (int nt = 0; nt < 4; ++nt) {
            int col = n0 + wn * 64 + nt * 16 + n;
            float bv = bias[col];
#pragma unroll
            for (int rg = 0; rg < 4; ++rg) {
                int row = m0 + wm * 64 + mt * 16 + q * 4 + rg;
                float v = acc[mt][nt][rg] + bv;
                if (EPI == 0) {
                    obf[(long)row * 1024 + (col & 255) * 4 + (col >> 8)] = f2bf(v);
                } else {
                    int bb = row & 127, tt = row >> 7;
                    of[((long)bb * 200 + tt) * 1024 + col] = sigmoidf_(v);
                }
            }
        }
    }
}

// ---------------- LSTM: batch-split, NO inter-WG sync ------------------------
// 32 WGs x 4 batch rows x 4 waves. Wave owns 64 hidden units = 16 col-tiles.
// 12 col-tiles (ub=0..2) resident in VGPRs (384), 4 (ub=3) streamed from LDS.
// acc processed one ub-group (4 tiles) at a time -> only acc[4]+vg[4] live.
// A-frag rows replicated x4 -> every lane holds all 4 batch rows' gates.
#define HB_STRIDE 264
__global__ __launch_bounds__(256, 1) void k_lstm(
    const unsigned short* __restrict__ xg,   // [200*128][256][4] bf16 gate-interleaved
    const unsigned short* __restrict__ Wbf,  // [1024][256] bf16
    unsigned short* __restrict__ h_all) {    // [200*128][256] bf16
    __shared__ unsigned short wlds[4 * 4 * 8 * 512];  // 128KB frag-linear (ub=3)
    __shared__ unsigned short hb[2][4 * HB_STRIDE];   // h state double buffer

    const int tid = threadIdx.x;
    const int w = tid >> 6, lane = tid & 63;
    const int n = lane & 15, q = lane >> 4;
    const int b0 = blockIdx.x * 4;

    // resident weights ub=0..2
    bf16x8 wr[3][4][8];
#pragma unroll
    for (int ub = 0; ub < 3; ++ub)
#pragma unroll
        for (int g = 0; g < 4; ++g) {
            const unsigned short* src = Wbf + (g * 256 + w * 64 + ub * 16 + n) * 256 + q * 8;
#pragma unroll
            for (int kk = 0; kk < 8; ++kk) wr[ub][g][kk] = ld8(src + kk * 32);
        }
    // LDS weights ub=3, frag-linear
#pragma unroll
    for (int g = 0; g < 4; ++g) {
        const unsigned short* src = Wbf + (g * 256 + w * 64 + 48 + n) * 256 + q * 8;
#pragma unroll
        for (int kk = 0; kk < 8; ++kk)
            *(uint4*)(&wlds[((w * 4 + g) * 8 + kk) * 512 + lane * 8]) =
                *(const uint4*)(src + kk * 32);
    }
    for (int i = tid; i < 4 * HB_STRIDE; i += 256) { hb[0][i] = 0; hb[1][i] = 0; }

    const int u = w * 64 + q * 16 + n;   // this lane's hidden unit (u = w*64 + lane)
    const unsigned short* xgp = xg + (long)b0 * 1024 + u * 4;

    // prefetch t=0: 4 rows x (4 gates packed in uint2)
    uint2 pxv[4];
#pragma unroll
    for (int r = 0; r < 4; ++r)
        pxv[r] = *(const uint2*)(xgp + (long)r * 1024);

    float cs[4] = {0.f, 0.f, 0.f, 0.f};
    __syncthreads();

    for (int t = 0; t < 200; ++t) {
        const int cur = t & 1, nxt = cur ^ 1;
        uint2 xv[4];
#pragma unroll
        for (int r = 0; r < 4; ++r) xv[r] = pxv[r];
        // prefetch next step (clamped at tail)
        const long toff = (long)((t + 1 < 200 ? t + 1 : 199)) * 128 * 1024;
#pragma unroll
        for (int r = 0; r < 4; ++r)
            pxv[r] = *(const uint2*)(xgp + toff + (long)r * 1024);

        // gates = h @ W^T, one ub-group at a time
        f32x4 vg[4] = {};
#pragma unroll
        for (int ub = 0; ub < 4; ++ub) {
            f32x4 acc[4] = {};
#pragma unroll
            for (int kk = 0; kk < 8; ++kk) {
                bf16x8 a = ld8(&hb[cur][(n & 3) * HB_STRIDE + kk * 32 + q * 8]);
                if (ub < 3) {
#pragma unroll
                    for (int g = 0; g < 4; ++g)
                        acc[g] = __builtin_amdgcn_mfma_f32_16x16x32_bf16(
                            a, wr[ub][g][kk], acc[g], 0, 0, 0);
                } else {
#pragma unroll
                    for (int g = 0; g < 4; ++g) {
                        bf16x8 wf = ld8(&wlds[((w * 4 + g) * 8 + kk) * 512 + lane * 8]);
                        acc[g] = __builtin_amdgcn_mfma_f32_16x16x32_bf16(
                            a, wf, acc[g], 0, 0, 0);
                    }
                }
            }
#pragma unroll
            for (int g = 0; g < 4; ++g)
                vg[g] = (q == ub) ? acc[g] : vg[g];
        }

        // elementwise LSTM update, 4 batch rows (acc row rg == batch row rg)
#pragma unroll
        for (int r = 0; r < 4; ++r) {
            float iv = vg[0][r] + bf2f((unsigned short)(xv[r].x & 0xFFFFu));
            float fv = vg[1][r] + bf2f((unsigned short)(xv[r].x >> 16));
            float gg = vg[2][r] + bf2f((unsigned short)(xv[r].y & 0xFFFFu));
            float ov = vg[3][r] + bf2f((unsigned short)(xv[r].y >> 16));
            float cn = sigmoidf_(fv) * cs[r] + sigmoidf_(iv) * tanhf_(gg);
            float hv = sigmoidf_(ov) * tanhf_(cn);
            cs[r] = cn;
            unsigned short hbv = f2bf(hv);
            hb[nxt][r * HB_STRIDE + u] = hbv;
            h_all[((long)t * 128 + b0 + r) * 256 + u] = hbv;
        }
        __syncthreads();
    }
}

extern "C" void kernel_launch(void* const* d_in, const int* in_sizes, int n_in,
                              void* d_out, int out_size, void* d_ws, size_t ws_size,
                              hipStream_t stream) {
    const int* c        = (const int*)d_in[0];
    const int* r        = (const int*)d_in[1];
    const int* rgap     = (const int*)d_in[2];
    const int* sgap     = (const int*)d_in[3];
    const int* pcount   = (const int*)d_in[4];
    const int* s_rgap   = (const int*)d_in[5];
    const int* s_sgap   = (const int*)d_in[6];
    const int* s_pcount = (const int*)d_in[7];
    const float* E      = (const float*)d_in[8];
    const float* cemb_W = (const float*)d_in[9];
    const float* W_ih   = (const float*)d_in[10];
    const float* W_hh   = (const float*)d_in[11];
    const float* b_ih   = (const float*)d_in[12];
    const float* b_hh   = (const float*)d_in[13];
    const float* out_W  = (const float*)d_in[14];
    const float* out_b  = (const float*)d_in[15];

    char* ws = (char*)d_ws;
    float* cWT            = (float*)(ws);                       // 131072 B
    float* bsum           = (float*)(ws + 131072);              // 4096 B
    unsigned short* Wbf   = (unsigned short*)(ws + 135168);     // 524288 B
    unsigned short* h_all = (unsigned short*)(ws + 659456);     // 13107200 B
    unsigned short* Abuf  = (unsigned short*)(ws + 13766656);   // 19660800 B
    unsigned short* xg    = (unsigned short*)(ws + 33427456);   // 52428800 B

    k_prep<<<256, 256, 0, stream>>>(cemb_W, b_ih, b_hh, W_hh, cWT, bsum, Wbf);
    k_build_in<<<25600, 128, 0, stream>>>(c, r, rgap, sgap, pcount, E, cWT, Abuf);
    k_gemm<0><<<dim3(200, 8), 256, 0, stream>>>(Abuf, W_ih, bsum, xg, nullptr);
    k_lstm<<<32, 256, 0, stream>>>(xg, Wbf, h_all);
    k_build_out<<<25600, 128, 0, stream>>>(s_rgap, s_sgap, s_pcount, h_all, cWT, Abuf);
    k_gemm<1><<<dim3(200, 8), 256, 0, stream>>>(Abuf, out_W, out_b, nullptr, (float*)d_out);
}

// Round 4
// 654.544 us; speedup vs baseline: 5.6681x; 1.0052x over previous
//
#include <hip/hip_runtime.h>

typedef __bf16 bf16x8 __attribute__((ext_vector_type(8)));
typedef float f32x4 __attribute__((ext_vector_type(4)));

__device__ __forceinline__ unsigned short f2bf(float f) {
    union { float f; unsigned u; } v; v.f = f;
    unsigned u = v.u;
    return (unsigned short)((u + 0x7FFFu + ((u >> 16) & 1u)) >> 16);
}
__device__ __forceinline__ float bf2f(unsigned short h) {
    union { unsigned u; float f; } v; v.u = ((unsigned)h) << 16;
    return v.f;
}
__device__ __forceinline__ bf16x8 ld8(const unsigned short* p) {
    union { uint4 u; bf16x8 b; } cv;
    cv.u = *(const uint4*)p;
    return cv.b;
}
__device__ __forceinline__ float sigmoidf_(float x) {
    return __builtin_amdgcn_rcpf(1.0f + __expf(-x));
}
__device__ __forceinline__ float tanhf_(float x) {
    float xc = fminf(fmaxf(x, -15.0f), 15.0f);
    float e = __expf(-2.0f * xc);
    return (1.0f - e) * __builtin_amdgcn_rcpf(1.0f + e);
}

// ---------------- prep: transpose cemb_W, bias sum, W_hh -> bf16 --------------
__global__ void k_prep(const float* __restrict__ cemb_W,
                       const float* __restrict__ b_ih, const float* __restrict__ b_hh,
                       const float* __restrict__ W_hh,
                       float* __restrict__ cWT, float* __restrict__ bsum,
                       unsigned short* __restrict__ Wbf) {
    int i = blockIdx.x * blockDim.x + threadIdx.x;
    int stride = gridDim.x * blockDim.x;
    const int TOT = 32768 + 1024 + 262144;
    for (; i < TOT; i += stride) {
        if (i < 32768) {
            int idx = i >> 8, e = i & 255;
            cWT[idx * 256 + e] = cemb_W[e * 128 + idx];   // cWT[i][e] = cemb_W[e][i]
        } else if (i < 33792) {
            int g = i - 32768;
            bsum[g] = b_ih[g] + b_hh[g];
        } else {
            int j = i - 33792;
            Wbf[j] = f2bf(W_hh[j]);
        }
    }
}

// ---------------- build A_in = [xemb * Cct, onehots] (bf16, rows m = t*128+b) --
__global__ __launch_bounds__(128) void k_build_in(
    const int* __restrict__ c, const int* __restrict__ r,
    const int* __restrict__ rgap, const int* __restrict__ sgap, const int* __restrict__ pcount,
    const float* __restrict__ E, const float* __restrict__ cWT,
    unsigned short* __restrict__ A) {
    int m = blockIdx.x;
    int b = m & 127, t = m >> 7;
    int src = b * 200 + t;
    int x = c[src] + 1024 * r[src];
    int ra = rgap[src], sa = 32 + sgap[src], pa = 64 + pcount[src];
    int e = threadIdx.x;
#pragma unroll
    for (int j = 0; j < 2; ++j) {
        int ee = e + j * 128;
        float cc = cWT[ra * 256 + ee] + cWT[sa * 256 + ee] + cWT[pa * 256 + ee];
        A[(long)m * 384 + ee] = f2bf(E[(long)x * 256 + ee] * cc);
    }
    A[(long)m * 384 + 256 + e] =
        (e == ra || e == sa || e == pa) ? (unsigned short)0x3F80 : (unsigned short)0;
}

// ---------------- build A_out = [h * Cct_shft, onehots] ----------------------
__global__ __launch_bounds__(128) void k_build_out(
    const int* __restrict__ rgap, const int* __restrict__ sgap, const int* __restrict__ pcount,
    const unsigned short* __restrict__ h_all, const float* __restrict__ cWT,
    unsigned short* __restrict__ A) {
    int m = blockIdx.x;
    int b = m & 127, t = m >> 7;
    int src = b * 200 + t;
    int ra = rgap[src], sa = 32 + sgap[src], pa = 64 + pcount[src];
    int e = threadIdx.x;
#pragma unroll
    for (int j = 0; j < 2; ++j) {
        int ee = e + j * 128;
        float cc = cWT[ra * 256 + ee] + cWT[sa * 256 + ee] + cWT[pa * 256 + ee];
        float v = bf2f(h_all[(long)m * 256 + ee]);
        A[(long)m * 384 + ee] = f2bf(v * cc);
    }
    A[(long)m * 384 + 256 + e] =
        (e == ra || e == sa || e == pa) ? (unsigned short)0x3F80 : (unsigned short)0;
}

// ---------------- GEMM: C[M,1024] = A[M,384](bf16) @ Bw[1024,384]^T + bias ----
// EPI==0: store bf16 xg, GATE-INTERLEAVED: xg[row*1024 + (col&255)*4 + (col>>8)]
// EPI==1: sigmoid, store f32 remapped to [B,T,V].
template<int EPI>
__global__ __launch_bounds__(256) void k_gemm(
    const unsigned short* __restrict__ A,
    const float* __restrict__ Bw,
    const float* __restrict__ bias,
    unsigned short* __restrict__ obf,
    float* __restrict__ of) {
    __shared__ unsigned short As[128 * 32];
    __shared__ unsigned short Bs[128 * 32];
    const int m0 = blockIdx.x * 128, n0 = blockIdx.y * 128;
    const int tid = threadIdx.x;
    const int wave = tid >> 6, lane = tid & 63;
    const int wm = wave >> 1, wn = wave & 1;
    const int n = lane & 15, q = lane >> 4;
    f32x4 acc[4][4] = {};
    for (int ks = 0; ks < 12; ++ks) {
        __syncthreads();
        {
            int rr = tid >> 2, cc = (tid & 3) * 8;
            const unsigned short* g = A + (long)(m0 + rr) * 384 + ks * 32 + cc;
            uint4 v0 = *(const uint4*)g;
            uint4 v1 = *(const uint4*)(g + 64 * 384);
            *(uint4*)(&As[rr * 32 + cc]) = v0;
            *(uint4*)(&As[(rr + 64) * 32 + cc]) = v1;
        }
        {
            int rr = tid >> 3, cc = (tid & 7) * 4;
#pragma unroll
            for (int j = 0; j < 4; ++j) {
                int row = j * 32 + rr;
                float4 f = *(const float4*)(Bw + (long)(n0 + row) * 384 + ks * 32 + cc);
                ushort4 h;
                h.x = f2bf(f.x); h.y = f2bf(f.y); h.z = f2bf(f.z); h.w = f2bf(f.w);
                *(ushort4*)(&Bs[row * 32 + cc]) = h;
            }
        }
        __syncthreads();
        bf16x8 af[4], bfr[4];
#pragma unroll
        for (int mt = 0; mt < 4; ++mt)
            af[mt] = ld8(&As[(wm * 64 + mt * 16 + n) * 32 + q * 8]);
#pragma unroll
        for (int nt = 0; nt < 4; ++nt)
            bfr[nt] = ld8(&Bs[(wn * 64 + nt * 16 + n) * 32 + q * 8]);
#pragma unroll
        for (int mt = 0; mt < 4; ++mt)
#pragma unroll
            for (int nt = 0; nt < 4; ++nt)
                acc[mt][nt] = __builtin_amdgcn_mfma_f32_16x16x32_bf16(
                    af[mt], bfr[nt], acc[mt][nt], 0, 0, 0);
    }
#pragma unroll
    for (int mt = 0; mt < 4; ++mt) {
#pragma unroll
        for (int nt = 0; nt < 4; ++nt) {
            int col = n0 + wn * 64 + nt * 16 + n;
            float bv = bias[col];
#pragma unroll
            for (int rg = 0; rg < 4; ++rg) {
                int row = m0 + wm * 64 + mt * 16 + q * 4 + rg;
                float v = acc[mt][nt][rg] + bv;
                if (EPI == 0) {
                    obf[(long)row * 1024 + (col & 255) * 4 + (col >> 8)] = f2bf(v);
                } else {
                    int bb = row & 127, tt = row >> 7;
                    of[((long)bb * 200 + tt) * 1024 + col] = sigmoidf_(v);
                }
            }
        }
    }
}

// ---------------- LSTM: batch-split, NO inter-WG sync ------------------------
// 32 WGs x 4 batch rows x 4 waves. Wave owns 64 hidden units = 16 col-tiles.
// 12 col-tiles (ub=0..2) resident in VGPRs (384), 4 (ub=3) streamed from LDS.
// ALL array indices compile-time (rule #20): ub loop fully unrolled, ub=3
// split into its own block. Only acc[4]+vg[4] live at a time.
#define HB_STRIDE 288
__global__ __launch_bounds__(256, 1) void k_lstm(
    const unsigned short* __restrict__ xg,   // [200*128][256][4] bf16 gate-interleaved
    const unsigned short* __restrict__ Wbf,  // [1024][256] bf16
    unsigned short* __restrict__ h_all) {    // [200*128][256] bf16
    __shared__ unsigned short wlds[4 * 4 * 8 * 512];  // 128KB frag-linear (ub=3)
    __shared__ unsigned short hb[2][4 * HB_STRIDE];   // h state double buffer

    const int tid = threadIdx.x;
    const int w = tid >> 6, lane = tid & 63;
    const int n = lane & 15, q = lane >> 4;
    const int b0 = blockIdx.x * 4;

    // resident weights ub=0..2 (384 VGPRs)
    bf16x8 wr[3][4][8];
#pragma unroll
    for (int ub = 0; ub < 3; ++ub)
#pragma unroll
        for (int g = 0; g < 4; ++g) {
            const unsigned short* src = Wbf + (g * 256 + w * 64 + ub * 16 + n) * 256 + q * 8;
#pragma unroll
            for (int kk = 0; kk < 8; ++kk) wr[ub][g][kk] = ld8(src + kk * 32);
        }
    // LDS weights ub=3, frag-linear
#pragma unroll
    for (int g = 0; g < 4; ++g) {
        const unsigned short* src = Wbf + (g * 256 + w * 64 + 48 + n) * 256 + q * 8;
#pragma unroll
        for (int kk = 0; kk < 8; ++kk)
            *(uint4*)(&wlds[((w * 4 + g) * 8 + kk) * 512 + lane * 8]) =
                *(const uint4*)(src + kk * 32);
    }
    for (int i = tid; i < 4 * HB_STRIDE; i += 256) { hb[0][i] = 0; hb[1][i] = 0; }

    const int u = w * 64 + q * 16 + n;   // this lane's hidden unit
    const unsigned short* xgp = xg + (long)b0 * 1024 + u * 4;

    // prefetch t=0: 4 rows x (4 gates packed in uint2)
    uint2 pxv[4];
#pragma unroll
    for (int r = 0; r < 4; ++r)
        pxv[r] = *(const uint2*)(xgp + (long)r * 1024);

    float cs[4] = {0.f, 0.f, 0.f, 0.f};
    __syncthreads();

    for (int t = 0; t < 200; ++t) {
        const int cur = t & 1, nxt = cur ^ 1;
        uint2 xv[4];
#pragma unroll
        for (int r = 0; r < 4; ++r) xv[r] = pxv[r];
        // prefetch next step (clamped at tail)
        const long toff = (long)((t + 1 < 200 ? t + 1 : 199)) * 128 * 1024;
#pragma unroll
        for (int r = 0; r < 4; ++r)
            pxv[r] = *(const uint2*)(xgp + toff + (long)r * 1024);

        // gates = h @ W^T : one ub-group (4 gate tiles) at a time
        f32x4 vg[4] = {};
#pragma unroll
        for (int ub = 0; ub < 3; ++ub) {    // fully unrolled: compile-time wr indices
            f32x4 acc[4] = {};
#pragma unroll
            for (int kk = 0; kk < 8; ++kk) {
                bf16x8 a = ld8(&hb[cur][(n & 3) * HB_STRIDE + kk * 32 + q * 8]);
#pragma unroll
                for (int g = 0; g < 4; ++g)
                    acc[g] = __builtin_amdgcn_mfma_f32_16x16x32_bf16(
                        a, wr[ub][g][kk], acc[g], 0, 0, 0);
            }
#pragma unroll
            for (int g = 0; g < 4; ++g)
                vg[g] = (q == ub) ? acc[g] : vg[g];
        }
        {   // ub == 3: streamed from LDS
            f32x4 acc[4] = {};
#pragma unroll
            for (int kk = 0; kk < 8; ++kk) {
                bf16x8 a = ld8(&hb[cur][(n & 3) * HB_STRIDE + kk * 32 + q * 8]);
#pragma unroll
                for (int g = 0; g < 4; ++g) {
                    bf16x8 wf = ld8(&wlds[((w * 4 + g) * 8 + kk) * 512 + lane * 8]);
                    acc[g] = __builtin_amdgcn_mfma_f32_16x16x32_bf16(
                        a, wf, acc[g], 0, 0, 0);
                }
            }
#pragma unroll
            for (int g = 0; g < 4; ++g)
                vg[g] = (q == 3) ? acc[g] : vg[g];
        }

        // elementwise LSTM update, 4 batch rows (acc row rg == batch row rg)
#pragma unroll
        for (int r = 0; r < 4; ++r) {
            float iv = vg[0][r] + bf2f((unsigned short)(xv[r].x & 0xFFFFu));
            float fv = vg[1][r] + bf2f((unsigned short)(xv[r].x >> 16));
            float gg = vg[2][r] + bf2f((unsigned short)(xv[r].y & 0xFFFFu));
            float ov = vg[3][r] + bf2f((unsigned short)(xv[r].y >> 16));
            float cn = sigmoidf_(fv) * cs[r] + sigmoidf_(iv) * tanhf_(gg);
            float hv = sigmoidf_(ov) * tanhf_(cn);
            cs[r] = cn;
            unsigned short hbv = f2bf(hv);
            hb[nxt][r * HB_STRIDE + u] = hbv;
            h_all[((long)t * 128 + b0 + r) * 256 + u] = hbv;
        }
        __syncthreads();
    }
}

extern "C" void kernel_launch(void* const* d_in, const int* in_sizes, int n_in,
                              void* d_out, int out_size, void* d_ws, size_t ws_size,
                              hipStream_t stream) {
    const int* c        = (const int*)d_in[0];
    const int* r        = (const int*)d_in[1];
    const int* rgap     = (const int*)d_in[2];
    const int* sgap     = (const int*)d_in[3];
    const int* pcount   = (const int*)d_in[4];
    const int* s_rgap   = (const int*)d_in[5];
    const int* s_sgap   = (const int*)d_in[6];
    const int* s_pcount = (const int*)d_in[7];
    const float* E      = (const float*)d_in[8];
    const float* cemb_W = (const float*)d_in[9];
    const float* W_ih   = (const float*)d_in[10];
    const float* W_hh   = (const float*)d_in[11];
    const float* b_ih   = (const float*)d_in[12];
    const float* b_hh   = (const float*)d_in[13];
    const float* out_W  = (const float*)d_in[14];
    const float* out_b  = (const float*)d_in[15];

    char* ws = (char*)d_ws;
    float* cWT            = (float*)(ws);                       // 131072 B
    float* bsum           = (float*)(ws + 131072);              // 4096 B
    unsigned short* Wbf   = (unsigned short*)(ws + 135168);     // 524288 B
    unsigned short* h_all = (unsigned short*)(ws + 659456);     // 13107200 B
    unsigned short* Abuf  = (unsigned short*)(ws + 13766656);   // 19660800 B
    unsigned short* xg    = (unsigned short*)(ws + 33427456);   // 52428800 B

    k_prep<<<256, 256, 0, stream>>>(cemb_W, b_ih, b_hh, W_hh, cWT, bsum, Wbf);
    k_build_in<<<25600, 128, 0, stream>>>(c, r, rgap, sgap, pcount, E, cWT, Abuf);
    k_gemm<0><<<dim3(200, 8), 256, 0, stream>>>(Abuf, W_ih, bsum, xg, nullptr);
    k_lstm<<<32, 256, 0, stream>>>(xg, Wbf, h_all);
    k_build_out<<<25600, 128, 0, stream>>>(s_rgap, s_sgap, s_pcount, h_all, cWT, Abuf);
    k_gemm<1><<<dim3(200, 8), 256, 0, stream>>>(Abuf, out_W, out_b, nullptr, (float*)d_out);
}